// Round 10
// baseline (194.101 us; speedup 1.0000x reference)
//
#include <hip/hip_runtime.h>
#include <hip/hip_bf16.h>
#include <hip/hip_cooperative_groups.h>
#include <cstddef>

namespace cg = cooperative_groups;

#define B_ 2
#define SL_ 2048
#define RATIO_ 16
#define SG_ 128
#define S_ 2176
#define D_ 512
#define H_ 8
#define HD_ 64
#define FF_ 1024
#define NC_ 2
#define NEG_ (-1.0e9f)
#define MINF_ (-1.0e30f)
#define MROWS_ (B_ * S_)   // 4352
#define GR_ (B_ * SG_)     // 256 global rows
#define KC_ 8              // split-K chunks for global-query attention

typedef __attribute__((ext_vector_type(8))) short short8;
typedef __attribute__((ext_vector_type(4))) float f32x4;

__device__ __forceinline__ void gll16(const void* g, void* l) {
    __builtin_amdgcn_global_load_lds((const __attribute__((address_space(1))) void*)g,
                                     (__attribute__((address_space(3))) void*)l, 16, 0, 0);
}
__device__ __forceinline__ unsigned short f2bf(float x) {
    __hip_bfloat16 h = __float2bfloat16(x);
    return *reinterpret_cast<unsigned short*>(&h);
}
__device__ __forceinline__ float wave_sum(float v) {
#pragma unroll
    for (int off = 1; off < 64; off <<= 1) v += __shfl_xor(v, off);
    return v;
}
#define BARRIER() do { asm volatile("" ::: "memory"); __builtin_amdgcn_s_barrier(); asm volatile("" ::: "memory"); } while (0)

// ================================================================ dispatch 1: prep
// blocks [0,2176): build x (2 rows each); blocks [2176,2688): weight transpose+convert.
__global__ __launch_bounds__(256) void prep_kernel(const int* __restrict__ ids,
                                                   const float* __restrict__ embed,
                                                   const float* __restrict__ gtok,
                                                   __hip_bfloat16* __restrict__ xb,
                                                   float* __restrict__ xg,
                                                   int* __restrict__ pad_all,
                                                   const float* __restrict__ qw,
                                                   const float* __restrict__ kw,
                                                   const float* __restrict__ vw,
                                                   const float* __restrict__ ow,
                                                   const float* __restrict__ f1w,
                                                   const float* __restrict__ f2w,
                                                   __hip_bfloat16* __restrict__ WqT,
                                                   __hip_bfloat16* __restrict__ WkvT,
                                                   __hip_bfloat16* __restrict__ WoT,
                                                   __hip_bfloat16* __restrict__ W1T,
                                                   __hip_bfloat16* __restrict__ W2T,
                                                   const float* __restrict__ k_b,
                                                   const float* __restrict__ v_b,
                                                   float* __restrict__ kvb) {
    __shared__ float tile[64][65];
    int bid = blockIdx.x, tid = threadIdx.x;
    if (bid < 2176) {
        int half = tid >> 7, lt = tid & 127;
        int row = bid * 2 + half;
        int b = row / S_, s = row % S_;
        const float* src;
        if (s < SL_) {
            int tok = ids[b * SL_ + s];
            src = embed + (size_t)tok * D_;
            if (lt == 0) pad_all[row] = (tok == 0) ? 1 : 0;
        } else {
            src = gtok;
            if (lt == 0) {
                int g = s - SL_;
                int allz = 1;
                for (int r = 0; r < RATIO_; ++r)
                    allz &= (ids[b * SL_ + g * RATIO_ + r] == 0) ? 1 : 0;
                pad_all[row] = allz;
            }
        }
        float4 v = ((const float4*)src)[lt];
        __hip_bfloat16 hb[4] = {__float2bfloat16(v.x), __float2bfloat16(v.y),
                                __float2bfloat16(v.z), __float2bfloat16(v.w)};
        *(uint2*)(xb + (size_t)row * D_ + lt * 4) = *(const uint2*)hb;
        if (s >= SL_)
            ((float4*)(xg + (size_t)(b * SG_ + s - SL_) * D_))[lt] = v;
        return;
    }
    int wbid = bid - 2176;
    if (wbid == 0) {
        for (int i = tid; i < 1024; i += 256)
            kvb[i] = (i < 512) ? k_b[i] : v_b[i - 512];
    }
    const float* W; __hip_bfloat16* Wt; int K, N, tx, ty;
    if (wbid < 192) {
        int which = wbid >> 6, id = wbid & 63;
        W = (which == 0) ? qw : (which == 1) ? kw : vw;
        Wt = (which == 0) ? WqT : (which == 1) ? WkvT : (WkvT + (size_t)512 * 512);
        K = 512; N = 512; tx = id & 7; ty = id >> 3;
    } else if (wbid < 256) {
        int id = wbid - 192; W = ow; Wt = WoT; K = 512; N = 512; tx = id & 7; ty = id >> 3;
    } else if (wbid < 384) {
        int id = wbid - 256; W = f1w; Wt = W1T; K = 512; N = 1024; tx = id & 15; ty = id >> 4;
    } else {
        int id = wbid - 384; W = f2w; Wt = W2T; K = 1024; N = 512; tx = id & 7; ty = id >> 3;
    }
    int n0 = tx * 64, k0 = ty * 64;
    int c = tid & 63, r4 = tid >> 6;
#pragma unroll
    for (int i = 0; i < 16; ++i) {
        int r = i * 4 + r4;
        tile[r][c] = W[(size_t)(k0 + r) * N + n0 + c];
    }
    __syncthreads();
#pragma unroll
    for (int i = 0; i < 16; ++i) {
        int n = i * 4 + r4;
        Wt[(size_t)(n0 + n) * K + k0 + c] = __float2bfloat16(tile[c][n]);
    }
}

// ================================================================ dispatch 2: fused KV (128^2) + Qg (64^2) GEMMs
__global__ __launch_bounds__(256) void qkv_kernel(const __hip_bfloat16* __restrict__ x_b,
                                                  const __hip_bfloat16* __restrict__ WkvT,
                                                  const float* __restrict__ kvb,
                                                  __hip_bfloat16* __restrict__ kv_bf,
                                                  const __hip_bfloat16* __restrict__ WqT,
                                                  const float* __restrict__ q_b,
                                                  __hip_bfloat16* __restrict__ qg_bf) {
    __shared__ short SA[2][4096];
    __shared__ short SB[2][4096];
    int bid = blockIdx.x, tid = threadIdx.x;
    int w = tid >> 6, lane = tid & 63;
    int wr = w >> 1, wc = w & 1;
    int p0 = tid * 16, rs = p0 >> 6, cs = p0 & 63;

    if (bid < 272) {
        // KV: C[4352,1024] = x_b @ WkvT^T
        const int K = 512, N = 1024;
        int m0 = (bid >> 3) * 128, n0 = (bid & 7) * 128;
        f32x4 acc[4][4];
#pragma unroll
        for (int m = 0; m < 4; ++m)
#pragma unroll
            for (int n = 0; n < 4; ++n) acc[m][n] = (f32x4){0.f, 0.f, 0.f, 0.f};
        const char* Ab = (const char*)x_b;
        const char* Bb = (const char*)WkvT;
        auto STAGE = [&](int buf, int k0) {
            gll16(Ab + ((size_t)(m0 + rs) * K + k0) * 2 + cs, (char*)SA[buf] + p0);
            gll16(Ab + ((size_t)(m0 + rs + 64) * K + k0) * 2 + cs, (char*)SA[buf] + p0 + 4096);
            gll16(Bb + ((size_t)(n0 + rs) * K + k0) * 2 + cs, (char*)SB[buf] + p0);
            gll16(Bb + ((size_t)(n0 + rs + 64) * K + k0) * 2 + cs, (char*)SB[buf] + p0 + 4096);
        };
        STAGE(0, 0);
        const int nk = K >> 5;
        for (int t = 0; t < nk; ++t) {
            int cur = t & 1;
            if (t + 1 < nk) {
                STAGE(cur ^ 1, (t + 1) << 5);
                asm volatile("s_waitcnt vmcnt(4)" ::: "memory");
            } else {
                asm volatile("s_waitcnt vmcnt(0)" ::: "memory");
            }
            BARRIER();
            short8 af[4], bfr[4];
#pragma unroll
            for (int m = 0; m < 4; ++m)
                af[m] = *(const short8*)&SA[cur][(wr * 64 + m * 16 + (lane & 15)) * 32 + (lane >> 4) * 8];
#pragma unroll
            for (int n = 0; n < 4; ++n)
                bfr[n] = *(const short8*)&SB[cur][(wc * 64 + n * 16 + (lane & 15)) * 32 + (lane >> 4) * 8];
#pragma unroll
            for (int m = 0; m < 4; ++m)
#pragma unroll
                for (int n = 0; n < 4; ++n)
                    acc[m][n] = __builtin_amdgcn_mfma_f32_16x16x32_bf16(af[m], bfr[n], acc[m][n], 0, 0, 0);
            BARRIER();
        }
        int rbase = m0 + wr * 64 + (lane >> 4) * 4;
        int cbase = n0 + wc * 64 + (lane & 15);
#pragma unroll
        for (int m = 0; m < 4; ++m)
#pragma unroll
            for (int n = 0; n < 4; ++n) {
                int col = cbase + n * 16;
                float bv = kvb[col];
#pragma unroll
                for (int j = 0; j < 4; ++j) {
                    int row = rbase + m * 16 + j;
                    kv_bf[(size_t)row * N + col] = __float2bfloat16(acc[m][n][j] + bv);
                }
            }
    } else {
        // Qg: C[256,512] = x_b[global rows] @ WqT^T (A-row remap)
        const int K = 512, N = 512;
        int idx = bid - 272;
        int m0 = (idx >> 3) * 64, n0 = (idx & 7) * 64;
        f32x4 acc[2][2];
#pragma unroll
        for (int m = 0; m < 2; ++m)
#pragma unroll
            for (int n = 0; n < 2; ++n) acc[m][n] = (f32x4){0.f, 0.f, 0.f, 0.f};
        int rl = m0 + rs;
        size_t arow = (size_t)((rl >> 7) * S_ + SL_ + (rl & 127));
        const char* Ab = (const char*)x_b;
        const char* Bb = (const char*)WqT;
        auto STAGE = [&](int buf, int k0) {
            gll16(Ab + (arow * K + k0) * 2 + cs, (char*)SA[buf] + p0);
            gll16(Bb + ((size_t)(n0 + rs) * K + k0) * 2 + cs, (char*)SB[buf] + p0);
        };
        STAGE(0, 0);
        const int nk = K >> 5;
        for (int t = 0; t < nk; ++t) {
            int cur = t & 1;
            if (t + 1 < nk) {
                STAGE(cur ^ 1, (t + 1) << 5);
                asm volatile("s_waitcnt vmcnt(2)" ::: "memory");
            } else {
                asm volatile("s_waitcnt vmcnt(0)" ::: "memory");
            }
            BARRIER();
            short8 af[2], bfr[2];
#pragma unroll
            for (int m = 0; m < 2; ++m)
                af[m] = *(const short8*)&SA[cur][(wr * 32 + m * 16 + (lane & 15)) * 32 + (lane >> 4) * 8];
#pragma unroll
            for (int n = 0; n < 2; ++n)
                bfr[n] = *(const short8*)&SB[cur][(wc * 32 + n * 16 + (lane & 15)) * 32 + (lane >> 4) * 8];
#pragma unroll
            for (int m = 0; m < 2; ++m)
#pragma unroll
                for (int n = 0; n < 2; ++n)
                    acc[m][n] = __builtin_amdgcn_mfma_f32_16x16x32_bf16(af[m], bfr[n], acc[m][n], 0, 0, 0);
            BARRIER();
        }
        int rbase = m0 + wr * 32 + (lane >> 4) * 4;
        int cbase = n0 + wc * 32 + (lane & 15);
#pragma unroll
        for (int m = 0; m < 2; ++m)
#pragma unroll
            for (int n = 0; n < 2; ++n) {
                int col = cbase + n * 16;
                float bv = q_b[col];
#pragma unroll
                for (int j = 0; j < 4; ++j) {
                    int row = rbase + m * 16 + j;
                    qg_bf[(size_t)row * N + col] = __float2bfloat16(acc[m][n][j] + bv);
                }
            }
    }
}

// ================================================================ dispatch 3: MFMA attention (global queries), split-K
#define ATT_LDS_ 28480

__global__ __launch_bounds__(256, 4) void attn_global_kernel(const __hip_bfloat16* __restrict__ Qg,
                                                             const __hip_bfloat16* __restrict__ KV,
                                                             const int* __restrict__ pad_all,
                                                             float* __restrict__ pacc,
                                                             float* __restrict__ pm,
                                                             float* __restrict__ pl) {
    __shared__ __align__(16) char smem[ATT_LDS_];
    short* Qs = (short*)(smem + 0);
    short* Ks = (short*)(smem + 4608);
    short* Vt = (short*)(smem + 13824);
    short* Pl = (short*)(smem + 23040);
    float* padv = (float*)(smem + 27648);
    float* msh  = (float*)(smem + 27968);
    float* lsh  = (float*)(smem + 28224);
    float* Osh  = (float*)smem;

    const int TS[KC_ + 1] = {0, 4, 8, 12, 17, 21, 25, 29, 34};
    int bid = blockIdx.x;
    int c  = bid & 7;
    int qt = (bid >> 3) & 3;
    int h  = (bid >> 5) & 7;
    int b  = bid >> 8;
    int i0c = qt * 32;
    int tid = threadIdx.x;
    int w = tid >> 6, lane = tid & 63;
    int qg = w >> 1, kh = w & 1;
    int cq = lane & 15, g4 = lane >> 4;
    const int* pad = pad_all + b * S_;
    const short* qgp = (const short*)Qg;
    const short* kv  = (const short*)KV;

    {
        int q = tid >> 3, g = tid & 7;
        short8 v = *(const short8*)(qgp + (size_t)(b * SG_ + i0c + q) * D_ + h * HD_ + g * 8);
        *(short8*)(Qs + q * 72 + g * 8) = v;
    }

    float mreg = MINF_, lreg = 0.0f;
    f32x4 ot0 = {0,0,0,0}, ot1 = {0,0,0,0}, ot2 = {0,0,0,0}, ot3 = {0,0,0,0};

    for (int t = TS[c]; t < TS[c + 1]; ++t) {
        int j0 = t * 64;
        __syncthreads();
        {
            int key = tid >> 2, g2 = tid & 3;
            size_t base = (size_t)(b * S_ + j0 + key) * 1024 + h * HD_;
#pragma unroll
            for (int gg = 0; gg < 2; ++gg) {
                int g = g2 + gg * 4;
                short8 kvv = *(const short8*)(kv + base + g * 8);
                *(short8*)(Ks + key * 72 + g * 8) = kvv;
                short8 vv = *(const short8*)(kv + base + 512 + g * 8);
#pragma unroll
                for (int i = 0; i < 8; ++i)
                    Vt[(g * 8 + i) * 72 + key] = vv[i];
            }
            if (tid < 64) padv[tid] = pad[j0 + tid] ? NEG_ : 0.0f;
        }
        __syncthreads();

        short8 qf0 = *(const short8*)(Qs + (qg * 16 + cq) * 72 + 0 + g4 * 8);
        short8 qf1 = *(const short8*)(Qs + (qg * 16 + cq) * 72 + 32 + g4 * 8);
        f32x4 st0 = {0,0,0,0}, st1 = {0,0,0,0};
        {
            short8 kf;
            kf = *(const short8*)(Ks + (kh * 32 + cq) * 72 + 0 + g4 * 8);
            st0 = __builtin_amdgcn_mfma_f32_16x16x32_bf16(kf, qf0, st0, 0, 0, 0);
            kf = *(const short8*)(Ks + (kh * 32 + cq) * 72 + 32 + g4 * 8);
            st0 = __builtin_amdgcn_mfma_f32_16x16x32_bf16(kf, qf1, st0, 0, 0, 0);
            kf = *(const short8*)(Ks + (kh * 32 + 16 + cq) * 72 + 0 + g4 * 8);
            st1 = __builtin_amdgcn_mfma_f32_16x16x32_bf16(kf, qf0, st1, 0, 0, 0);
            kf = *(const short8*)(Ks + (kh * 32 + 16 + cq) * 72 + 32 + g4 * 8);
            st1 = __builtin_amdgcn_mfma_f32_16x16x32_bf16(kf, qf1, st1, 0, 0, 0);
        }
        float sarr[8];
#pragma unroll
        for (int mt = 0; mt < 2; ++mt)
#pragma unroll
            for (int j = 0; j < 4; ++j) {
                int k = kh * 32 + mt * 16 + g4 * 4 + j;
                sarr[mt * 4 + j] = (mt ? st1[j] : st0[j]) * 0.125f + padv[k];
            }
        float cmax = sarr[0];
#pragma unroll
        for (int i = 1; i < 8; ++i) cmax = fmaxf(cmax, sarr[i]);
        cmax = fmaxf(cmax, __shfl_xor(cmax, 16));
        cmax = fmaxf(cmax, __shfl_xor(cmax, 32));
        float mnew = fmaxf(mreg, cmax);
        float fac = __expf(mreg - mnew);
        float parr[8], psum = 0.0f;
#pragma unroll
        for (int i = 0; i < 8; ++i) { parr[i] = __expf(sarr[i] - mnew); psum += parr[i]; }
        psum += __shfl_xor(psum, 16);
        psum += __shfl_xor(psum, 32);
        lreg = lreg * fac + psum;
        mreg = mnew;
        ot0 *= fac; ot1 *= fac; ot2 *= fac; ot3 *= fac;
#pragma unroll
        for (int mt = 0; mt < 2; ++mt) {
            unsigned int lo = (unsigned int)f2bf(parr[mt * 4 + 0]) | ((unsigned int)f2bf(parr[mt * 4 + 1]) << 16);
            unsigned int hi = (unsigned int)f2bf(parr[mt * 4 + 2]) | ((unsigned int)f2bf(parr[mt * 4 + 3]) << 16);
            unsigned int* dst = (unsigned int*)(Pl + (qg * 16 + cq) * 72 + kh * 32 + mt * 16 + g4 * 4);
            dst[0] = lo; dst[1] = hi;
        }
        short8 pf = *(const short8*)(Pl + (qg * 16 + cq) * 72 + kh * 32 + g4 * 8);
        {
            short8 vf;
            vf = *(const short8*)(Vt + (0 * 16 + cq) * 72 + kh * 32 + g4 * 8);
            ot0 = __builtin_amdgcn_mfma_f32_16x16x32_bf16(vf, pf, ot0, 0, 0, 0);
            vf = *(const short8*)(Vt + (1 * 16 + cq) * 72 + kh * 32 + g4 * 8);
            ot1 = __builtin_amdgcn_mfma_f32_16x16x32_bf16(vf, pf, ot1, 0, 0, 0);
            vf = *(const short8*)(Vt + (2 * 16 + cq) * 72 + kh * 32 + g4 * 8);
            ot2 = __builtin_amdgcn_mfma_f32_16x16x32_bf16(vf, pf, ot2, 0, 0, 0);
            vf = *(const short8*)(Vt + (3 * 16 + cq) * 72 + kh * 32 + g4 * 8);
            ot3 = __builtin_amdgcn_mfma_f32_16x16x32_bf16(vf, pf, ot3, 0, 0, 0);
        }
    }

    __syncthreads();
    if (g4 == 0) {
        msh[(qg * 2 + kh) * 16 + cq] = mreg;
        lsh[(qg * 2 + kh) * 16 + cq] = lreg;
    }
    __syncthreads();
    {
        float m0 = msh[(qg * 2 + 0) * 16 + cq], m1 = msh[(qg * 2 + 1) * 16 + cq];
        float Mm = fmaxf(m0, m1);
        float e_self = __expf(mreg - Mm);
        f32x4 o;
        o = ot0 * e_self; *(f32x4*)(Osh + ((qg * 2 + kh) * 16 + cq) * 68 + 0  + g4 * 4) = o;
        o = ot1 * e_self; *(f32x4*)(Osh + ((qg * 2 + kh) * 16 + cq) * 68 + 16 + g4 * 4) = o;
        o = ot2 * e_self; *(f32x4*)(Osh + ((qg * 2 + kh) * 16 + cq) * 68 + 32 + g4 * 4) = o;
        o = ot3 * e_self; *(f32x4*)(Osh + ((qg * 2 + kh) * 16 + cq) * 68 + 48 + g4 * 4) = o;
    }
    __syncthreads();
    {
        int q_all = tid >> 3, d0 = (tid & 7) * 8;
        int qg2 = q_all >> 4, ql = q_all & 15;
        float mm0 = msh[(qg2 * 2 + 0) * 16 + ql], mm1 = msh[(qg2 * 2 + 1) * 16 + ql];
        float MM = fmaxf(mm0, mm1);
        float lt = lsh[(qg2 * 2 + 0) * 16 + ql] * __expf(mm0 - MM) +
                   lsh[(qg2 * 2 + 1) * 16 + ql] * __expf(mm1 - MM);
        int prow = ((c * B_ + b) * H_ + h) * SG_ + qt * 32 + q_all;
#pragma unroll
        for (int i = 0; i < 8; ++i) {
            float a = Osh[((qg2 * 2 + 0) * 16 + ql) * 68 + d0 + i] +
                      Osh[((qg2 * 2 + 1) * 16 + ql) * 68 + d0 + i];
            pacc[(size_t)prow * HD_ + d0 + i] = a;
        }
        if ((tid & 7) == 0) { pm[prow] = MM; pl[prow] = lt; }
    }
}

// ================================================================ dispatch 4: cooperative tail
__device__ __forceinline__ void gemm64_body(short (&As)[2][2048], short (&Bs)[2][2048],
                                            const __hip_bfloat16* A, const __hip_bfloat16* Bt,
                                            const float* bias, const float* Res, void* Cout,
                                            int N, int K, int flags, int m0, int n0) {
    int tid = threadIdx.x;
    int w = tid >> 6, lane = tid & 63;
    int wr = w >> 1, wc = w & 1;
    f32x4 acc[2][2];
#pragma unroll
    for (int m = 0; m < 2; ++m)
#pragma unroll
        for (int n = 0; n < 2; ++n) acc[m][n] = (f32x4){0.f, 0.f, 0.f, 0.f};
    int p0 = tid * 16, rs = p0 >> 6, cs = p0 & 63;
    const char* Ab = (const char*)A;
    const char* Bb = (const char*)Bt;
    auto STAGE = [&](int buf, int k0) {
        gll16(Ab + ((size_t)(m0 + rs) * K + k0) * 2 + cs, (char*)As[buf] + p0);
        gll16(Bb + ((size_t)(n0 + rs) * K + k0) * 2 + cs, (char*)Bs[buf] + p0);
    };
    STAGE(0, 0);
    int nk = K >> 5;
    for (int t = 0; t < nk; ++t) {
        int cur = t & 1;
        if (t + 1 < nk) {
            STAGE(cur ^ 1, (t + 1) << 5);
            asm volatile("s_waitcnt vmcnt(2)" ::: "memory");
        } else {
            asm volatile("s_waitcnt vmcnt(0)" ::: "memory");
        }
        BARRIER();
        short8 af[2], bfr[2];
#pragma unroll
        for (int m = 0; m < 2; ++m)
            af[m] = *(const short8*)&As[cur][(wr * 32 + m * 16 + (lane & 15)) * 32 + (lane >> 4) * 8];
#pragma unroll
        for (int n = 0; n < 2; ++n)
            bfr[n] = *(const short8*)&Bs[cur][(wc * 32 + n * 16 + (lane & 15)) * 32 + (lane >> 4) * 8];
#pragma unroll
        for (int m = 0; m < 2; ++m)
#pragma unroll
            for (int n = 0; n < 2; ++n)
                acc[m][n] = __builtin_amdgcn_mfma_f32_16x16x32_bf16(af[m], bfr[n], acc[m][n], 0, 0, 0);
        BARRIER();
    }
    int rbase = m0 + wr * 32 + (lane >> 4) * 4;
    int cbase = n0 + wc * 32 + (lane & 15);
#pragma unroll
    for (int m = 0; m < 2; ++m)
#pragma unroll
        for (int n = 0; n < 2; ++n) {
            int col = cbase + n * 16;
            float bv = bias[col];
#pragma unroll
            for (int j = 0; j < 4; ++j) {
                int row = rbase + m * 16 + j;
                float v = acc[m][n][j] + bv;
                if (flags & 4) v += Res[(size_t)row * N + col];
                if (flags & 1) v = fmaxf(v, 0.0f);
                if (flags & 2)
                    ((__hip_bfloat16*)Cout)[(size_t)row * N + col] = __float2bfloat16(v);
                else
                    ((float*)Cout)[(size_t)row * N + col] = v;
            }
        }
}

__device__ __forceinline__ void ln_row(const float* A, const float* g, const float* be,
                                       float* out, __hip_bfloat16* outb, int wb, int row,
                                       float* ws1, float* ws2) {
    int tid = threadIdx.x;
    size_t base = (size_t)row * D_;
    float x0 = A[base + tid];
    float x1 = A[base + tid + 256];
    float s1 = x0 + x1, s2 = x0 * x0 + x1 * x1;
    for (int off = 1; off < 64; off <<= 1) {
        s1 += __shfl_xor(s1, off);
        s2 += __shfl_xor(s2, off);
    }
    int wid = tid >> 6;
    if ((tid & 63) == 0) { ws1[wid] = s1; ws2[wid] = s2; }
    __syncthreads();
    s1 = ws1[0] + ws1[1] + ws1[2] + ws1[3];
    s2 = ws2[0] + ws2[1] + ws2[2] + ws2[3];
    float mean = s1 * (1.0f / D_);
    float var  = s2 * (1.0f / D_) - mean * mean;
    float rstd = rsqrtf(var + 1e-5f);
    float o0 = (x0 - mean) * rstd * g[tid]       + be[tid];
    float o1 = (x1 - mean) * rstd * g[tid + 256] + be[tid + 256];
    out[base + tid]       = o0;
    out[base + tid + 256] = o1;
    if (wb) {
        outb[base + tid]       = __float2bfloat16(o0);
        outb[base + tid + 256] = __float2bfloat16(o1);
    }
    __syncthreads();   // ws1/ws2 reused by next row in the caller's loop
}

struct TailP {
    const float* pacc; const float* pm; const float* pl;
    __hip_bfloat16* og;
    const __hip_bfloat16* WoT; const float* o_b; const float* xg; float* tmpA;
    const float* ln1_g; const float* ln1_b; float* x1g; __hip_bfloat16* x1g_b;
    const __hip_bfloat16* W1T; const float* ff1_b; __hip_bfloat16* ffh;
    const __hip_bfloat16* W2T; const float* ff2_b; float* tmpB;
    const float* ln2_g; const float* ln2_b; float* x2g;
    const int* pad_all; const float* w1; float* part; const float* w2; float* out;
};

__global__ __launch_bounds__(256) void tail_kernel(TailP p) {
    cg::grid_group gg = cg::this_grid();
    __shared__ short TA[2][2048];
    __shared__ short TB[2][2048];
    __shared__ float ws1[4], ws2[4];
    __shared__ float wrow[SG_];
    __shared__ float zpart[4][64];
    __shared__ float zgs[64];
    __shared__ float r0s[4], r1s[4];
    int bid = blockIdx.x, tid = threadIdx.x;

    // ---- A: split-K combine -> og (bf16). 2048 (b,gq,h) items over 256 waves.
    {
        int wave_g = bid * 4 + (tid >> 6);
        int lane = tid & 63;
#pragma unroll
        for (int i = 0; i < 8; ++i) {
            int item = wave_g * 8 + i;
            int gq = item & (SG_ - 1);
            int h  = (item >> 7) & 7;
            int b  = item >> 10;
            float M = MINF_;
#pragma unroll
            for (int c = 0; c < KC_; ++c)
                M = fmaxf(M, p.pm[((c * B_ + b) * H_ + h) * SG_ + gq]);
            float L = 0.0f, Ov = 0.0f;
#pragma unroll
            for (int c = 0; c < KC_; ++c) {
                int pidx = ((c * B_ + b) * H_ + h) * SG_ + gq;
                float e = __expf(p.pm[pidx] - M);
                L += p.pl[pidx] * e;
                Ov += p.pacc[(size_t)pidx * HD_ + lane] * e;
            }
            p.og[(size_t)(b * SG_ + gq) * D_ + h * HD_ + lane] = __float2bfloat16(Ov / L);
        }
    }
    __threadfence(); gg.sync();

    // ---- B: O-proj + residual -> tmpA (f32), 32 tiles
    if (bid < 32)
        gemm64_body(TA, TB, p.og, p.WoT, p.o_b, p.xg, p.tmpA, 512, 512, 4, (bid >> 3) * 64, (bid & 7) * 64);
    __threadfence(); gg.sync();

    // ---- C: LN1 -> x1g (f32) + x1g_b (bf16), 4 rows/block
    for (int r = 0; r < 4; ++r)
        ln_row(p.tmpA, p.ln1_g, p.ln1_b, p.x1g, p.x1g_b, 1, bid * 4 + r, ws1, ws2);
    __threadfence(); gg.sync();

    // ---- D: FF1 relu -> ffh (bf16), 64 tiles
    gemm64_body(TA, TB, p.x1g_b, p.W1T, p.ff1_b, nullptr, p.ffh, 1024, 512, 1 | 2, (bid >> 4) * 64, (bid & 15) * 64);
    __threadfence(); gg.sync();

    // ---- E: FF2 + residual -> tmpB (f32), 32 tiles
    if (bid < 32)
        gemm64_body(TA, TB, p.ffh, p.W2T, p.ff2_b, p.x1g, p.tmpB, 512, 1024, 4, (bid >> 3) * 64, (bid & 7) * 64);
    __threadfence(); gg.sync();

    // ---- F: LN2 -> x2g (f32)
    for (int r = 0; r < 4; ++r)
        ln_row(p.tmpB, p.ln2_g, p.ln2_b, p.x2g, nullptr, 0, bid * 4 + r, ws1, ws2);
    __threadfence(); gg.sync();

    // ---- G: pool + w1 GEMV partial, 16 blocks
    if (bid < 16) {
        int kc = bid & 7, b = bid >> 3;
        if (tid < SG_) wrow[tid] = p.pad_all[b * S_ + SL_ + tid] ? 0.0f : 1.0f;
        __syncthreads();
        int j = tid & 63, grp = tid >> 6;
        float a = 0.0f;
#pragma unroll 8
        for (int g = grp; g < SG_; g += 4)
            a = fmaf(wrow[g], p.x2g[(size_t)(b * SG_ + g) * D_ + kc * 64 + j], a);
        zpart[grp][j] = a;
        __syncthreads();
        if (tid < 64) {
            float cnt = 0.0f;
#pragma unroll 16
            for (int g = 0; g < SG_; ++g) cnt += wrow[g];
            zgs[tid] = (zpart[0][tid] + zpart[1][tid] + zpart[2][tid] + zpart[3][tid]) / cnt;
        }
        __syncthreads();
        float s = 0.0f;
#pragma unroll 8
        for (int d = 0; d < 64; ++d)
            s = fmaf(zgs[d], p.w1[(size_t)(kc * 64 + d) * 256 + tid], s);
        p.part[(b * 8 + kc) * 256 + tid] = s;
    }
    __threadfence(); gg.sync();

    // ---- H: relu + w2 -> out, 2 blocks
    if (bid < 2) {
        int b = bid;
        float hsum = 0.0f;
#pragma unroll
        for (int kc = 0; kc < 8; ++kc) hsum += p.part[(b * 8 + kc) * 256 + tid];
        hsum = fmaxf(hsum, 0.0f);
        float o0 = hsum * p.w2[(size_t)tid * NC_ + 0];
        float o1 = hsum * p.w2[(size_t)tid * NC_ + 1];
        o0 = wave_sum(o0);
        o1 = wave_sum(o1);
        if ((tid & 63) == 0) { r0s[tid >> 6] = o0; r1s[tid >> 6] = o1; }
        __syncthreads();
        if (tid == 0) {
            p.out[b * NC_ + 0] = r0s[0] + r0s[1] + r0s[2] + r0s[3];
            p.out[b * NC_ + 1] = r1s[0] + r1s[1] + r1s[2] + r1s[3];
        }
    }
}

// ---------------------------------------------------------------- launch
extern "C" void kernel_launch(void* const* d_in, const int* in_sizes, int n_in,
                              void* d_out, int out_size, void* d_ws, size_t ws_size,
                              hipStream_t stream) {
    const int*   ids    = (const int*)d_in[0];
    const float* embed  = (const float*)d_in[1];
    const float* gtok   = (const float*)d_in[2];
    const float* q_w    = (const float*)d_in[4];
    const float* q_b    = (const float*)d_in[5];
    const float* k_w    = (const float*)d_in[6];
    const float* k_b    = (const float*)d_in[7];
    const float* v_w    = (const float*)d_in[8];
    const float* v_b    = (const float*)d_in[9];
    const float* o_w    = (const float*)d_in[10];
    const float* o_b    = (const float*)d_in[11];
    const float* ln1_g  = (const float*)d_in[12];
    const float* ln1_b  = (const float*)d_in[13];
    const float* ln2_g  = (const float*)d_in[14];
    const float* ln2_b  = (const float*)d_in[15];
    const float* ff1_w  = (const float*)d_in[16];
    const float* ff1_b  = (const float*)d_in[17];
    const float* ff2_w  = (const float*)d_in[18];
    const float* ff2_b  = (const float*)d_in[19];
    const float* cls_w1 = (const float*)d_in[20];
    const float* cls_w2 = (const float*)d_in[21];

    char* ws = (char*)d_ws;
    __hip_bfloat16* x_b     = (__hip_bfloat16*)(ws + 0);          //  4,456,448
    __hip_bfloat16* kv_bf   = (__hip_bfloat16*)(ws + 4456448);    //  8,912,896
    __hip_bfloat16* qg_bf   = (__hip_bfloat16*)(ws + 13369344);   //    262,144
    __hip_bfloat16* og_bf   = (__hip_bfloat16*)(ws + 13631488);   //    262,144
    float*          xg_f32  = (float*)(ws + 13893632);            //    524,288
    float*          tmpA    = (float*)(ws + 14417920);            //    524,288
    float*          x1g     = (float*)(ws + 14942208);            //    524,288
    __hip_bfloat16* x1g_b   = (__hip_bfloat16*)(ws + 15466496);   //    262,144
    __hip_bfloat16* ffh_b   = (__hip_bfloat16*)(ws + 15728640);   //    524,288
    float*          tmpB    = (float*)(ws + 16252928);            //    524,288
    float*          x2g     = (float*)(ws + 16777216);            //    524,288
    __hip_bfloat16* WqT     = (__hip_bfloat16*)(ws + 17301504);   //    524,288
    __hip_bfloat16* WkvT    = (__hip_bfloat16*)(ws + 17825792);   //  1,048,576
    __hip_bfloat16* WoT     = (__hip_bfloat16*)(ws + 18874368);   //    524,288
    __hip_bfloat16* W1T     = (__hip_bfloat16*)(ws + 19398656);   //  1,048,576
    __hip_bfloat16* W2T     = (__hip_bfloat16*)(ws + 20447232);   //  1,048,576
    float*          kvb     = (float*)(ws + 21495808);            //      4,096
    int*            pad_all = (int*)(ws + 21499904);              //     17,408
    float*          pacc    = (float*)(ws + 21520384);            //  4,194,304
    float*          pm      = (float*)(ws + 25714688);            //     65,536
    float*          pl      = (float*)(ws + 25780224);            //     65,536
    float*          clspart = (float*)(ws + 25845760);            //     16,384

    prep_kernel<<<2688, 256, 0, stream>>>(ids, embed, gtok, x_b, xg_f32, pad_all,
                                          q_w, k_w, v_w, o_w, ff1_w, ff2_w,
                                          WqT, WkvT, WoT, W1T, W2T, k_b, v_b, kvb);

    qkv_kernel<<<304, 256, 0, stream>>>(x_b, WkvT, kvb, kv_bf, WqT, q_b, qg_bf);

    attn_global_kernel<<<512, 256, 0, stream>>>(qg_bf, kv_bf, pad_all, pacc, pm, pl);

    TailP tp;
    tp.pacc = pacc; tp.pm = pm; tp.pl = pl;
    tp.og = og_bf;
    tp.WoT = WoT; tp.o_b = o_b; tp.xg = xg_f32; tp.tmpA = tmpA;
    tp.ln1_g = ln1_g; tp.ln1_b = ln1_b; tp.x1g = x1g; tp.x1g_b = x1g_b;
    tp.W1T = W1T; tp.ff1_b = ff1_b; tp.ffh = ffh_b;
    tp.W2T = W2T; tp.ff2_b = ff2_b; tp.tmpB = tmpB;
    tp.ln2_g = ln2_g; tp.ln2_b = ln2_b; tp.x2g = x2g;
    tp.pad_all = pad_all; tp.w1 = cls_w1; tp.part = clspart; tp.w2 = cls_w2;
    tp.out = (float*)d_out;
    void* kargs[] = {(void*)&tp};
    hipLaunchCooperativeKernel((void*)tail_kernel, dim3(64), dim3(256), kargs, 0, stream);
}

// Round 11
// 87.481 us; speedup vs baseline: 2.2188x; 2.2188x over previous
//
#include <hip/hip_runtime.h>
#include <hip/hip_bf16.h>
#include <cstddef>

#define B_ 2
#define SL_ 2048
#define RATIO_ 16
#define SG_ 128
#define S_ 2176
#define D_ 512
#define H_ 8
#define HD_ 64
#define FF_ 1024
#define NC_ 2
#define NEG_ (-1.0e9f)
#define MINF_ (-1.0e30f)
#define MROWS_ (B_ * S_)   // 4352
#define GR_ (B_ * SG_)     // 256 global rows
#define KC_ 8              // split-K chunks for global-query attention

typedef __attribute__((ext_vector_type(8))) short short8;
typedef __attribute__((ext_vector_type(4))) float f32x4;

__device__ __forceinline__ void gll16(const void* g, void* l) {
    __builtin_amdgcn_global_load_lds((const __attribute__((address_space(1))) void*)g,
                                     (__attribute__((address_space(3))) void*)l, 16, 0, 0);
}
__device__ __forceinline__ unsigned short f2bf(float x) {
    __hip_bfloat16 h = __float2bfloat16(x);
    return *reinterpret_cast<unsigned short*>(&h);
}
__device__ __forceinline__ float wave_sum(float v) {
#pragma unroll
    for (int off = 1; off < 64; off <<= 1) v += __shfl_xor(v, off);
    return v;
}
#define BARRIER() do { asm volatile("" ::: "memory"); __builtin_amdgcn_s_barrier(); asm volatile("" ::: "memory"); } while (0)

// ================================================================ dispatch 1: prep (build x + weight transpose)
__global__ __launch_bounds__(256) void prep_kernel(const int* __restrict__ ids,
                                                   const float* __restrict__ embed,
                                                   const float* __restrict__ gtok,
                                                   __hip_bfloat16* __restrict__ xb,
                                                   float* __restrict__ xg,
                                                   int* __restrict__ pad_all,
                                                   const float* __restrict__ qw,
                                                   const float* __restrict__ kw,
                                                   const float* __restrict__ vw,
                                                   const float* __restrict__ ow,
                                                   const float* __restrict__ f1w,
                                                   const float* __restrict__ f2w,
                                                   __hip_bfloat16* __restrict__ WqT,
                                                   __hip_bfloat16* __restrict__ WkvT,
                                                   __hip_bfloat16* __restrict__ WoT,
                                                   __hip_bfloat16* __restrict__ W1T,
                                                   __hip_bfloat16* __restrict__ W2T,
                                                   const float* __restrict__ k_b,
                                                   const float* __restrict__ v_b,
                                                   float* __restrict__ kvb) {
    __shared__ float tile[64][65];
    int bid = blockIdx.x, tid = threadIdx.x;
    if (bid < 2176) {
        int half = tid >> 7, lt = tid & 127;
        int row = bid * 2 + half;
        int b = row / S_, s = row % S_;
        const float* src;
        if (s < SL_) {
            int tok = ids[b * SL_ + s];
            src = embed + (size_t)tok * D_;
            if (lt == 0) pad_all[row] = (tok == 0) ? 1 : 0;
        } else {
            src = gtok;
            if (lt == 0) {
                int g = s - SL_;
                int allz = 1;
                for (int r = 0; r < RATIO_; ++r)
                    allz &= (ids[b * SL_ + g * RATIO_ + r] == 0) ? 1 : 0;
                pad_all[row] = allz;
            }
        }
        float4 v = ((const float4*)src)[lt];
        __hip_bfloat16 hb[4] = {__float2bfloat16(v.x), __float2bfloat16(v.y),
                                __float2bfloat16(v.z), __float2bfloat16(v.w)};
        *(uint2*)(xb + (size_t)row * D_ + lt * 4) = *(const uint2*)hb;
        if (s >= SL_)
            ((float4*)(xg + (size_t)(b * SG_ + s - SL_) * D_))[lt] = v;
        return;
    }
    int wbid = bid - 2176;
    if (wbid == 0) {
        for (int i = tid; i < 1024; i += 256)
            kvb[i] = (i < 512) ? k_b[i] : v_b[i - 512];
    }
    const float* W; __hip_bfloat16* Wt; int K, N, tx, ty;
    if (wbid < 192) {
        int which = wbid >> 6, id = wbid & 63;
        W = (which == 0) ? qw : (which == 1) ? kw : vw;
        Wt = (which == 0) ? WqT : (which == 1) ? WkvT : (WkvT + (size_t)512 * 512);
        K = 512; N = 512; tx = id & 7; ty = id >> 3;
    } else if (wbid < 256) {
        int id = wbid - 192; W = ow; Wt = WoT; K = 512; N = 512; tx = id & 7; ty = id >> 3;
    } else if (wbid < 384) {
        int id = wbid - 256; W = f1w; Wt = W1T; K = 512; N = 1024; tx = id & 15; ty = id >> 4;
    } else {
        int id = wbid - 384; W = f2w; Wt = W2T; K = 1024; N = 512; tx = id & 7; ty = id >> 3;
    }
    int n0 = tx * 64, k0 = ty * 64;
    int c = tid & 63, r4 = tid >> 6;
#pragma unroll
    for (int i = 0; i < 16; ++i) {
        int r = i * 4 + r4;
        tile[r][c] = W[(size_t)(k0 + r) * N + n0 + c];
    }
    __syncthreads();
#pragma unroll
    for (int i = 0; i < 16; ++i) {
        int n = i * 4 + r4;
        Wt[(size_t)(n0 + n) * K + k0 + c] = __float2bfloat16(tile[c][n]);
    }
}

// ================================================================ dispatch 2: fused KV (128^2) + Qg (64^2) GEMMs
__global__ __launch_bounds__(256) void qkv_kernel(const __hip_bfloat16* __restrict__ x_b,
                                                  const __hip_bfloat16* __restrict__ WkvT,
                                                  const float* __restrict__ kvb,
                                                  __hip_bfloat16* __restrict__ kv_bf,
                                                  const __hip_bfloat16* __restrict__ WqT,
                                                  const float* __restrict__ q_b,
                                                  __hip_bfloat16* __restrict__ qg_bf) {
    __shared__ short SA[2][4096];
    __shared__ short SB[2][4096];
    int bid = blockIdx.x, tid = threadIdx.x;
    int w = tid >> 6, lane = tid & 63;
    int wr = w >> 1, wc = w & 1;
    int p0 = tid * 16, rs = p0 >> 6, cs = p0 & 63;

    if (bid < 272) {
        const int K = 512, N = 1024;
        int m0 = (bid >> 3) * 128, n0 = (bid & 7) * 128;
        f32x4 acc[4][4];
#pragma unroll
        for (int m = 0; m < 4; ++m)
#pragma unroll
            for (int n = 0; n < 4; ++n) acc[m][n] = (f32x4){0.f, 0.f, 0.f, 0.f};
        const char* Ab = (const char*)x_b;
        const char* Bb = (const char*)WkvT;
        auto STAGE = [&](int buf, int k0) {
            gll16(Ab + ((size_t)(m0 + rs) * K + k0) * 2 + cs, (char*)SA[buf] + p0);
            gll16(Ab + ((size_t)(m0 + rs + 64) * K + k0) * 2 + cs, (char*)SA[buf] + p0 + 4096);
            gll16(Bb + ((size_t)(n0 + rs) * K + k0) * 2 + cs, (char*)SB[buf] + p0);
            gll16(Bb + ((size_t)(n0 + rs + 64) * K + k0) * 2 + cs, (char*)SB[buf] + p0 + 4096);
        };
        STAGE(0, 0);
        const int nk = K >> 5;
        for (int t = 0; t < nk; ++t) {
            int cur = t & 1;
            if (t + 1 < nk) {
                STAGE(cur ^ 1, (t + 1) << 5);
                asm volatile("s_waitcnt vmcnt(4)" ::: "memory");
            } else {
                asm volatile("s_waitcnt vmcnt(0)" ::: "memory");
            }
            BARRIER();
            short8 af[4], bfr[4];
#pragma unroll
            for (int m = 0; m < 4; ++m)
                af[m] = *(const short8*)&SA[cur][(wr * 64 + m * 16 + (lane & 15)) * 32 + (lane >> 4) * 8];
#pragma unroll
            for (int n = 0; n < 4; ++n)
                bfr[n] = *(const short8*)&SB[cur][(wc * 64 + n * 16 + (lane & 15)) * 32 + (lane >> 4) * 8];
#pragma unroll
            for (int m = 0; m < 4; ++m)
#pragma unroll
                for (int n = 0; n < 4; ++n)
                    acc[m][n] = __builtin_amdgcn_mfma_f32_16x16x32_bf16(af[m], bfr[n], acc[m][n], 0, 0, 0);
            BARRIER();
        }
        int rbase = m0 + wr * 64 + (lane >> 4) * 4;
        int cbase = n0 + wc * 64 + (lane & 15);
#pragma unroll
        for (int m = 0; m < 4; ++m)
#pragma unroll
            for (int n = 0; n < 4; ++n) {
                int col = cbase + n * 16;
                float bv = kvb[col];
#pragma unroll
                for (int j = 0; j < 4; ++j) {
                    int row = rbase + m * 16 + j;
                    kv_bf[(size_t)row * N + col] = __float2bfloat16(acc[m][n][j] + bv);
                }
            }
    } else {
        const int K = 512, N = 512;
        int idx = bid - 272;
        int m0 = (idx >> 3) * 64, n0 = (idx & 7) * 64;
        f32x4 acc[2][2];
#pragma unroll
        for (int m = 0; m < 2; ++m)
#pragma unroll
            for (int n = 0; n < 2; ++n) acc[m][n] = (f32x4){0.f, 0.f, 0.f, 0.f};
        int rl = m0 + rs;
        size_t arow = (size_t)((rl >> 7) * S_ + SL_ + (rl & 127));
        const char* Ab = (const char*)x_b;
        const char* Bb = (const char*)WqT;
        auto STAGE = [&](int buf, int k0) {
            gll16(Ab + (arow * K + k0) * 2 + cs, (char*)SA[buf] + p0);
            gll16(Bb + ((size_t)(n0 + rs) * K + k0) * 2 + cs, (char*)SB[buf] + p0);
        };
        STAGE(0, 0);
        const int nk = K >> 5;
        for (int t = 0; t < nk; ++t) {
            int cur = t & 1;
            if (t + 1 < nk) {
                STAGE(cur ^ 1, (t + 1) << 5);
                asm volatile("s_waitcnt vmcnt(2)" ::: "memory");
            } else {
                asm volatile("s_waitcnt vmcnt(0)" ::: "memory");
            }
            BARRIER();
            short8 af[2], bfr[2];
#pragma unroll
            for (int m = 0; m < 2; ++m)
                af[m] = *(const short8*)&SA[cur][(wr * 32 + m * 16 + (lane & 15)) * 32 + (lane >> 4) * 8];
#pragma unroll
            for (int n = 0; n < 2; ++n)
                bfr[n] = *(const short8*)&SB[cur][(wc * 32 + n * 16 + (lane & 15)) * 32 + (lane >> 4) * 8];
#pragma unroll
            for (int m = 0; m < 2; ++m)
#pragma unroll
                for (int n = 0; n < 2; ++n)
                    acc[m][n] = __builtin_amdgcn_mfma_f32_16x16x32_bf16(af[m], bfr[n], acc[m][n], 0, 0, 0);
            BARRIER();
        }
        int rbase = m0 + wr * 32 + (lane >> 4) * 4;
        int cbase = n0 + wc * 32 + (lane & 15);
#pragma unroll
        for (int m = 0; m < 2; ++m)
#pragma unroll
            for (int n = 0; n < 2; ++n) {
                int col = cbase + n * 16;
                float bv = q_b[col];
#pragma unroll
                for (int j = 0; j < 4; ++j) {
                    int row = rbase + m * 16 + j;
                    qg_bf[(size_t)row * N + col] = __float2bfloat16(acc[m][n][j] + bv);
                }
            }
    }
}

// ---------------------------------------------------------------- 64x64 bf16 MFMA GEMM (tail), dbuf
// flags: 1 = relu, 2 = bf16 output, 4 = add residual
__global__ __launch_bounds__(256) void gemm64_kernel(const __hip_bfloat16* __restrict__ A,
                                                     const __hip_bfloat16* __restrict__ Bt,
                                                     const float* __restrict__ bias,
                                                     const float* __restrict__ Res,
                                                     void* __restrict__ Cout,
                                                     int N, int K, int flags) {
    __shared__ short As[2][64 * 32];
    __shared__ short Bs[2][64 * 32];
    int tid = threadIdx.x;
    int m0 = blockIdx.y * 64, n0 = blockIdx.x * 64;
    int w = tid >> 6, lane = tid & 63;
    int wr = w >> 1, wc = w & 1;

    f32x4 acc[2][2];
#pragma unroll
    for (int m = 0; m < 2; ++m)
#pragma unroll
        for (int n = 0; n < 2; ++n)
            acc[m][n] = (f32x4){0.f, 0.f, 0.f, 0.f};

    int p0 = tid * 16, rs = p0 >> 6, cs = p0 & 63;
    const char* Ab = (const char*)A;
    const char* Bb = (const char*)Bt;

    auto STAGE = [&](int buf, int k0) {
        gll16(Ab + ((size_t)(m0 + rs) * K + k0) * 2 + cs, (char*)As[buf] + p0);
        gll16(Bb + ((size_t)(n0 + rs) * K + k0) * 2 + cs, (char*)Bs[buf] + p0);
    };
    STAGE(0, 0);
    int nk = K >> 5;
    for (int t = 0; t < nk; ++t) {
        int cur = t & 1;
        if (t + 1 < nk) {
            STAGE(cur ^ 1, (t + 1) << 5);
            asm volatile("s_waitcnt vmcnt(2)" ::: "memory");
        } else {
            asm volatile("s_waitcnt vmcnt(0)" ::: "memory");
        }
        BARRIER();
        short8 af[2], bfr[2];
#pragma unroll
        for (int m = 0; m < 2; ++m)
            af[m] = *(const short8*)&As[cur][(wr * 32 + m * 16 + (lane & 15)) * 32 + (lane >> 4) * 8];
#pragma unroll
        for (int n = 0; n < 2; ++n)
            bfr[n] = *(const short8*)&Bs[cur][(wc * 32 + n * 16 + (lane & 15)) * 32 + (lane >> 4) * 8];
#pragma unroll
        for (int m = 0; m < 2; ++m)
#pragma unroll
            for (int n = 0; n < 2; ++n)
                acc[m][n] = __builtin_amdgcn_mfma_f32_16x16x32_bf16(af[m], bfr[n], acc[m][n], 0, 0, 0);
        BARRIER();
    }

    int rbase = m0 + wr * 32 + (lane >> 4) * 4;
    int cbase = n0 + wc * 32 + (lane & 15);
#pragma unroll
    for (int m = 0; m < 2; ++m)
#pragma unroll
        for (int n = 0; n < 2; ++n) {
            int col = cbase + n * 16;
            float bv = bias[col];
#pragma unroll
            for (int j = 0; j < 4; ++j) {
                int row = rbase + m * 16 + j;
                float v = acc[m][n][j] + bv;
                if (flags & 4) v += Res[(size_t)row * N + col];
                if (flags & 1) v = fmaxf(v, 0.0f);
                if (flags & 2)
                    ((__hip_bfloat16*)Cout)[(size_t)row * N + col] = __float2bfloat16(v);
                else
                    ((float*)Cout)[(size_t)row * N + col] = v;
            }
        }
}

// ================================================================ dispatch 3: MFMA attention (global queries), split-K
#define ATT_LDS_ 28480

__global__ __launch_bounds__(256, 4) void attn_global_kernel(const __hip_bfloat16* __restrict__ Qg,
                                                             const __hip_bfloat16* __restrict__ KV,
                                                             const int* __restrict__ pad_all,
                                                             float* __restrict__ pacc,
                                                             float* __restrict__ pm,
                                                             float* __restrict__ pl) {
    __shared__ __align__(16) char smem[ATT_LDS_];
    short* Qs = (short*)(smem + 0);
    short* Ks = (short*)(smem + 4608);
    short* Vt = (short*)(smem + 13824);
    short* Pl = (short*)(smem + 23040);
    float* padv = (float*)(smem + 27648);
    float* msh  = (float*)(smem + 27968);
    float* lsh  = (float*)(smem + 28224);
    float* Osh  = (float*)smem;

    const int TS[KC_ + 1] = {0, 4, 8, 12, 17, 21, 25, 29, 34};
    int bid = blockIdx.x;
    int c  = bid & 7;
    int qt = (bid >> 3) & 3;
    int h  = (bid >> 5) & 7;
    int b  = bid >> 8;
    int i0c = qt * 32;
    int tid = threadIdx.x;
    int w = tid >> 6, lane = tid & 63;
    int qg = w >> 1, kh = w & 1;
    int cq = lane & 15, g4 = lane >> 4;
    const int* pad = pad_all + b * S_;
    const short* qgp = (const short*)Qg;
    const short* kv  = (const short*)KV;

    {
        int q = tid >> 3, g = tid & 7;
        short8 v = *(const short8*)(qgp + (size_t)(b * SG_ + i0c + q) * D_ + h * HD_ + g * 8);
        *(short8*)(Qs + q * 72 + g * 8) = v;
    }

    float mreg = MINF_, lreg = 0.0f;
    f32x4 ot0 = {0,0,0,0}, ot1 = {0,0,0,0}, ot2 = {0,0,0,0}, ot3 = {0,0,0,0};

    for (int t = TS[c]; t < TS[c + 1]; ++t) {
        int j0 = t * 64;
        __syncthreads();
        {
            int key = tid >> 2, g2 = tid & 3;
            size_t base = (size_t)(b * S_ + j0 + key) * 1024 + h * HD_;
#pragma unroll
            for (int gg = 0; gg < 2; ++gg) {
                int g = g2 + gg * 4;
                short8 kvv = *(const short8*)(kv + base + g * 8);
                *(short8*)(Ks + key * 72 + g * 8) = kvv;
                short8 vv = *(const short8*)(kv + base + 512 + g * 8);
#pragma unroll
                for (int i = 0; i < 8; ++i)
                    Vt[(g * 8 + i) * 72 + key] = vv[i];
            }
            if (tid < 64) padv[tid] = pad[j0 + tid] ? NEG_ : 0.0f;
        }
        __syncthreads();

        short8 qf0 = *(const short8*)(Qs + (qg * 16 + cq) * 72 + 0 + g4 * 8);
        short8 qf1 = *(const short8*)(Qs + (qg * 16 + cq) * 72 + 32 + g4 * 8);
        f32x4 st0 = {0,0,0,0}, st1 = {0,0,0,0};
        {
            short8 kf;
            kf = *(const short8*)(Ks + (kh * 32 + cq) * 72 + 0 + g4 * 8);
            st0 = __builtin_amdgcn_mfma_f32_16x16x32_bf16(kf, qf0, st0, 0, 0, 0);
            kf = *(const short8*)(Ks + (kh * 32 + cq) * 72 + 32 + g4 * 8);
            st0 = __builtin_amdgcn_mfma_f32_16x16x32_bf16(kf, qf1, st0, 0, 0, 0);
            kf = *(const short8*)(Ks + (kh * 32 + 16 + cq) * 72 + 0 + g4 * 8);
            st1 = __builtin_amdgcn_mfma_f32_16x16x32_bf16(kf, qf0, st1, 0, 0, 0);
            kf = *(const short8*)(Ks + (kh * 32 + 16 + cq) * 72 + 32 + g4 * 8);
            st1 = __builtin_amdgcn_mfma_f32_16x16x32_bf16(kf, qf1, st1, 0, 0, 0);
        }
        float sarr[8];
#pragma unroll
        for (int mt = 0; mt < 2; ++mt)
#pragma unroll
            for (int j = 0; j < 4; ++j) {
                int k = kh * 32 + mt * 16 + g4 * 4 + j;
                sarr[mt * 4 + j] = (mt ? st1[j] : st0[j]) * 0.125f + padv[k];
            }
        float cmax = sarr[0];
#pragma unroll
        for (int i = 1; i < 8; ++i) cmax = fmaxf(cmax, sarr[i]);
        cmax = fmaxf(cmax, __shfl_xor(cmax, 16));
        cmax = fmaxf(cmax, __shfl_xor(cmax, 32));
        float mnew = fmaxf(mreg, cmax);
        float fac = __expf(mreg - mnew);
        float parr[8], psum = 0.0f;
#pragma unroll
        for (int i = 0; i < 8; ++i) { parr[i] = __expf(sarr[i] - mnew); psum += parr[i]; }
        psum += __shfl_xor(psum, 16);
        psum += __shfl_xor(psum, 32);
        lreg = lreg * fac + psum;
        mreg = mnew;
        ot0 *= fac; ot1 *= fac; ot2 *= fac; ot3 *= fac;
#pragma unroll
        for (int mt = 0; mt < 2; ++mt) {
            unsigned int lo = (unsigned int)f2bf(parr[mt * 4 + 0]) | ((unsigned int)f2bf(parr[mt * 4 + 1]) << 16);
            unsigned int hi = (unsigned int)f2bf(parr[mt * 4 + 2]) | ((unsigned int)f2bf(parr[mt * 4 + 3]) << 16);
            unsigned int* dst = (unsigned int*)(Pl + (qg * 16 + cq) * 72 + kh * 32 + mt * 16 + g4 * 4);
            dst[0] = lo; dst[1] = hi;
        }
        short8 pf = *(const short8*)(Pl + (qg * 16 + cq) * 72 + kh * 32 + g4 * 8);
        {
            short8 vf;
            vf = *(const short8*)(Vt + (0 * 16 + cq) * 72 + kh * 32 + g4 * 8);
            ot0 = __builtin_amdgcn_mfma_f32_16x16x32_bf16(vf, pf, ot0, 0, 0, 0);
            vf = *(const short8*)(Vt + (1 * 16 + cq) * 72 + kh * 32 + g4 * 8);
            ot1 = __builtin_amdgcn_mfma_f32_16x16x32_bf16(vf, pf, ot1, 0, 0, 0);
            vf = *(const short8*)(Vt + (2 * 16 + cq) * 72 + kh * 32 + g4 * 8);
            ot2 = __builtin_amdgcn_mfma_f32_16x16x32_bf16(vf, pf, ot2, 0, 0, 0);
            vf = *(const short8*)(Vt + (3 * 16 + cq) * 72 + kh * 32 + g4 * 8);
            ot3 = __builtin_amdgcn_mfma_f32_16x16x32_bf16(vf, pf, ot3, 0, 0, 0);
        }
    }

    __syncthreads();
    if (g4 == 0) {
        msh[(qg * 2 + kh) * 16 + cq] = mreg;
        lsh[(qg * 2 + kh) * 16 + cq] = lreg;
    }
    __syncthreads();
    {
        float m0 = msh[(qg * 2 + 0) * 16 + cq], m1 = msh[(qg * 2 + 1) * 16 + cq];
        float Mm = fmaxf(m0, m1);
        float e_self = __expf(mreg - Mm);
        f32x4 o;
        o = ot0 * e_self; *(f32x4*)(Osh + ((qg * 2 + kh) * 16 + cq) * 68 + 0  + g4 * 4) = o;
        o = ot1 * e_self; *(f32x4*)(Osh + ((qg * 2 + kh) * 16 + cq) * 68 + 16 + g4 * 4) = o;
        o = ot2 * e_self; *(f32x4*)(Osh + ((qg * 2 + kh) * 16 + cq) * 68 + 32 + g4 * 4) = o;
        o = ot3 * e_self; *(f32x4*)(Osh + ((qg * 2 + kh) * 16 + cq) * 68 + 48 + g4 * 4) = o;
    }
    __syncthreads();
    {
        int q_all = tid >> 3, d0 = (tid & 7) * 8;
        int qg2 = q_all >> 4, ql = q_all & 15;
        float mm0 = msh[(qg2 * 2 + 0) * 16 + ql], mm1 = msh[(qg2 * 2 + 1) * 16 + ql];
        float MM = fmaxf(mm0, mm1);
        float lt = lsh[(qg2 * 2 + 0) * 16 + ql] * __expf(mm0 - MM) +
                   lsh[(qg2 * 2 + 1) * 16 + ql] * __expf(mm1 - MM);
        int prow = ((c * B_ + b) * H_ + h) * SG_ + qt * 32 + q_all;
#pragma unroll
        for (int i = 0; i < 8; ++i) {
            float a = Osh[((qg2 * 2 + 0) * 16 + ql) * 68 + d0 + i] +
                      Osh[((qg2 * 2 + 1) * 16 + ql) * 68 + d0 + i];
            pacc[(size_t)prow * HD_ + d0 + i] = a;
        }
        if ((tid & 7) == 0) { pm[prow] = MM; pl[prow] = lt; }
    }
}

__global__ __launch_bounds__(256) void attn_combine_kernel(const float* __restrict__ pacc,
                                                           const float* __restrict__ pm,
                                                           const float* __restrict__ pl,
                                                           __hip_bfloat16* __restrict__ Og) {
    int wave = (int)((blockIdx.x * (size_t)blockDim.x + threadIdx.x) >> 6);
    int lane = threadIdx.x & 63;
    int gq = wave & (SG_ - 1);
    int h  = (wave >> 7) & 7;
    int b  = wave >> 10;

    float M = MINF_;
#pragma unroll
    for (int c = 0; c < KC_; ++c) {
        int pidx = ((c * B_ + b) * H_ + h) * SG_ + gq;
        M = fmaxf(M, pm[pidx]);
    }
    float L = 0.0f, Ov = 0.0f;
#pragma unroll
    for (int c = 0; c < KC_; ++c) {
        int pidx = ((c * B_ + b) * H_ + h) * SG_ + gq;
        float e = __expf(pm[pidx] - M);
        L += pl[pidx] * e;
        Ov += pacc[(size_t)pidx * HD_ + lane] * e;
    }
    Og[(size_t)(b * SG_ + gq) * D_ + h * HD_ + lane] = __float2bfloat16(Ov / L);
}

// ---------------------------------------------------------------- LN (input already has residual added)
__global__ __launch_bounds__(256) void ln_kernel(const float* __restrict__ A,
                                                 const float* __restrict__ g,
                                                 const float* __restrict__ be,
                                                 float* __restrict__ out,
                                                 __hip_bfloat16* __restrict__ outb,
                                                 int wb) {
    int row = blockIdx.x;
    int tid = threadIdx.x;
    size_t base = (size_t)row * D_;
    float x0 = A[base + tid];
    float x1 = A[base + tid + 256];
    float s1 = x0 + x1;
    float s2 = x0 * x0 + x1 * x1;
    for (int off = 1; off < 64; off <<= 1) {
        s1 += __shfl_xor(s1, off);
        s2 += __shfl_xor(s2, off);
    }
    __shared__ float ws1[4], ws2[4];
    int wid = tid >> 6;
    if ((tid & 63) == 0) { ws1[wid] = s1; ws2[wid] = s2; }
    __syncthreads();
    s1 = ws1[0] + ws1[1] + ws1[2] + ws1[3];
    s2 = ws2[0] + ws2[1] + ws2[2] + ws2[3];
    float mean = s1 * (1.0f / D_);
    float var  = s2 * (1.0f / D_) - mean * mean;
    float rstd = rsqrtf(var + 1e-5f);
    float o0 = (x0 - mean) * rstd * g[tid]       + be[tid];
    float o1 = (x1 - mean) * rstd * g[tid + 256] + be[tid + 256];
    out[base + tid]       = o0;
    out[base + tid + 256] = o1;
    if (wb) {
        outb[base + tid]       = __float2bfloat16(o0);
        outb[base + tid + 256] = __float2bfloat16(o1);
    }
}

// ---------------------------------------------------------------- classifier stage 1: per-slice pool + w1 GEMV
__global__ __launch_bounds__(256) void cls_part_kernel(const float* __restrict__ x2g,
                                                       const int* __restrict__ pad_all,
                                                       const float* __restrict__ w1,
                                                       float* __restrict__ part) {
    int kc = blockIdx.x, b = blockIdx.y, tid = threadIdx.x;
    __shared__ float wrow[SG_];
    __shared__ float zpart[4][64];
    __shared__ float zgs[64];
    if (tid < SG_) wrow[tid] = pad_all[b * S_ + SL_ + tid] ? 0.0f : 1.0f;
    __syncthreads();

    int j = tid & 63, grp = tid >> 6;
    float a = 0.0f;
#pragma unroll 8
    for (int g = grp; g < SG_; g += 4)
        a = fmaf(wrow[g], x2g[(size_t)(b * SG_ + g) * D_ + kc * 64 + j], a);
    zpart[grp][j] = a;
    __syncthreads();
    if (tid < 64) {
        float cnt = 0.0f;
#pragma unroll 16
        for (int g = 0; g < SG_; ++g) cnt += wrow[g];
        zgs[tid] = (zpart[0][tid] + zpart[1][tid] + zpart[2][tid] + zpart[3][tid]) / cnt;
    }
    __syncthreads();

    float s = 0.0f;
#pragma unroll 8
    for (int d = 0; d < 64; ++d)
        s = fmaf(zgs[d], w1[(size_t)(kc * 64 + d) * 256 + tid], s);
    part[(b * 8 + kc) * 256 + tid] = s;
}

__global__ __launch_bounds__(256) void cls_fin_kernel(const float* __restrict__ part,
                                                      const float* __restrict__ w2,
                                                      float* __restrict__ out) {
    int b = blockIdx.x, n = threadIdx.x;
    float hsum = 0.0f;
#pragma unroll
    for (int kc = 0; kc < 8; ++kc) hsum += part[(b * 8 + kc) * 256 + n];
    hsum = fmaxf(hsum, 0.0f);
    float o0 = hsum * w2[(size_t)n * NC_ + 0];
    float o1 = hsum * w2[(size_t)n * NC_ + 1];
    o0 = wave_sum(o0);
    o1 = wave_sum(o1);
    __shared__ float r0[4], r1[4];
    if ((n & 63) == 0) { r0[n >> 6] = o0; r1[n >> 6] = o1; }
    __syncthreads();
    if (n == 0) {
        out[b * NC_ + 0] = r0[0] + r0[1] + r0[2] + r0[3];
        out[b * NC_ + 1] = r1[0] + r1[1] + r1[2] + r1[3];
    }
}

// ---------------------------------------------------------------- launch
extern "C" void kernel_launch(void* const* d_in, const int* in_sizes, int n_in,
                              void* d_out, int out_size, void* d_ws, size_t ws_size,
                              hipStream_t stream) {
    const int*   ids    = (const int*)d_in[0];
    const float* embed  = (const float*)d_in[1];
    const float* gtok   = (const float*)d_in[2];
    const float* q_w    = (const float*)d_in[4];
    const float* q_b    = (const float*)d_in[5];
    const float* k_w    = (const float*)d_in[6];
    const float* k_b    = (const float*)d_in[7];
    const float* v_w    = (const float*)d_in[8];
    const float* v_b    = (const float*)d_in[9];
    const float* o_w    = (const float*)d_in[10];
    const float* o_b    = (const float*)d_in[11];
    const float* ln1_g  = (const float*)d_in[12];
    const float* ln1_b  = (const float*)d_in[13];
    const float* ln2_g  = (const float*)d_in[14];
    const float* ln2_b  = (const float*)d_in[15];
    const float* ff1_w  = (const float*)d_in[16];
    const float* ff1_b  = (const float*)d_in[17];
    const float* ff2_w  = (const float*)d_in[18];
    const float* ff2_b  = (const float*)d_in[19];
    const float* cls_w1 = (const float*)d_in[20];
    const float* cls_w2 = (const float*)d_in[21];

    char* ws = (char*)d_ws;
    __hip_bfloat16* x_b     = (__hip_bfloat16*)(ws + 0);          //  4,456,448
    __hip_bfloat16* kv_bf   = (__hip_bfloat16*)(ws + 4456448);    //  8,912,896
    __hip_bfloat16* qg_bf   = (__hip_bfloat16*)(ws + 13369344);   //    262,144
    __hip_bfloat16* og_bf   = (__hip_bfloat16*)(ws + 13631488);   //    262,144
    float*          xg_f32  = (float*)(ws + 13893632);            //    524,288
    float*          tmpA    = (float*)(ws + 14417920);            //    524,288
    float*          x1g     = (float*)(ws + 14942208);            //    524,288
    __hip_bfloat16* x1g_b   = (__hip_bfloat16*)(ws + 15466496);   //    262,144
    __hip_bfloat16* ffh_b   = (__hip_bfloat16*)(ws + 15728640);   //    524,288
    float*          tmpB    = (float*)(ws + 16252928);            //    524,288
    float*          x2g     = (float*)(ws + 16777216);            //    524,288
    __hip_bfloat16* WqT     = (__hip_bfloat16*)(ws + 17301504);   //    524,288
    __hip_bfloat16* WkvT    = (__hip_bfloat16*)(ws + 17825792);   //  1,048,576
    __hip_bfloat16* WoT     = (__hip_bfloat16*)(ws + 18874368);   //    524,288
    __hip_bfloat16* W1T     = (__hip_bfloat16*)(ws + 19398656);   //  1,048,576
    __hip_bfloat16* W2T     = (__hip_bfloat16*)(ws + 20447232);   //  1,048,576
    float*          kvb     = (float*)(ws + 21495808);            //      4,096
    int*            pad_all = (int*)(ws + 21499904);              //     17,408
    float*          pacc    = (float*)(ws + 21520384);            //  4,194,304
    float*          pm      = (float*)(ws + 25714688);            //     65,536
    float*          pl      = (float*)(ws + 25780224);            //     65,536
    float*          clspart = (float*)(ws + 25845760);            //     16,384

    prep_kernel<<<2688, 256, 0, stream>>>(ids, embed, gtok, x_b, xg_f32, pad_all,
                                          q_w, k_w, v_w, o_w, ff1_w, ff2_w,
                                          WqT, WkvT, WoT, W1T, W2T, k_b, v_b, kvb);

    qkv_kernel<<<304, 256, 0, stream>>>(x_b, WkvT, kvb, kv_bf, WqT, q_b, qg_bf);

    attn_global_kernel<<<512, 256, 0, stream>>>(qg_bf, kv_bf, pad_all, pacc, pm, pl);
    attn_combine_kernel<<<512, 256, 0, stream>>>(pacc, pm, pl, og_bf);

    // tail: 256 rows only (ordinary dispatches — r10's grid.sync cost ~20us each)
    gemm64_kernel<<<dim3(8, 4), 256, 0, stream>>>(og_bf, WoT, o_b, xg_f32, tmpA, 512, 512, 4);
    ln_kernel<<<GR_, 256, 0, stream>>>(tmpA, ln1_g, ln1_b, x1g, x1g_b, 1);
    gemm64_kernel<<<dim3(16, 4), 256, 0, stream>>>(x1g_b, W1T, ff1_b, nullptr, ffh_b, 1024, 512, 1 | 2);
    gemm64_kernel<<<dim3(8, 4), 256, 0, stream>>>(ffh_b, W2T, ff2_b, x1g, tmpB, 512, 1024, 4);
    ln_kernel<<<GR_, 256, 0, stream>>>(tmpB, ln2_g, ln2_b, x2g, nullptr, 0);

    cls_part_kernel<<<dim3(8, B_), 256, 0, stream>>>(x2g, pad_all, cls_w1, clspart);
    cls_fin_kernel<<<B_, 256, 0, stream>>>(clspart, cls_w2, (float*)d_out);
}